// Round 1
// baseline (393.881 us; speedup 1.0000x reference)
//
#include <hip/hip_runtime.h>

// Fused MLP: relu(x@W0^T+b0) -> relu(@W1^T+b1) -> @W2^T+b2
// x: [N,32] f32, W0: [64,32], W1: [64,64], W2: [4,64], out: [N,4] f32.
// Memory-bound: 288 MB traffic -> ~46us roofline @6.3TB/s.
// Strategy: bf16 MFMA 16x16x32, weights register-resident, per-wave LDS
// handoff (D-layout -> A-layout) between layers, hi/lo split-bf16 on the
// A operand for ~fp32 input precision. No barriers (per-wave LDS only).

typedef float f4 __attribute__((ext_vector_type(4)));
typedef __bf16 bf16x8 __attribute__((ext_vector_type(8)));

#define MFMA(a, b, c) __builtin_amdgcn_mfma_f32_16x16x32_bf16(a, b, c, 0, 0, 0)

// A/B fragment element mapping for mfma_f32_16x16x32_bf16:
//   lane = idx + 16*((k>>2)&3),  elem e: k = 16*(e>>2) + 4*(lane>>4) + (e&3)
// i.e. elems 0-3 <- 4 consecutive f32 at col 4g, elems 4-7 <- at col 16+4g.

__device__ __forceinline__ bf16x8 cvt8(f4 a, f4 b) {
  bf16x8 o;
#pragma unroll
  for (int e = 0; e < 4; ++e) {
    o[e]     = (__bf16)a[e];
    o[e + 4] = (__bf16)b[e];
  }
  return o;
}

__device__ __forceinline__ void split8(f4 a, f4 b, bf16x8& hi, bf16x8& lo) {
#pragma unroll
  for (int e = 0; e < 4; ++e) {
    float fa = a[e], fb = b[e];
    __bf16 ha = (__bf16)fa, hb = (__bf16)fb;
    hi[e]     = ha;
    hi[e + 4] = hb;
    lo[e]     = (__bf16)(fa - (float)ha);
    lo[e + 4] = (__bf16)(fb - (float)hb);
  }
}

#define TILES_PER_WAVE 16
#define ROWS_PER_BLOCK (4 * TILES_PER_WAVE * 16)  // 1024

__global__ __launch_bounds__(256) void fastmlp_kernel(
    const float* __restrict__ x, const float* __restrict__ W0,
    const float* __restrict__ b0, const float* __restrict__ W1,
    const float* __restrict__ b1, const float* __restrict__ W2,
    const float* __restrict__ b2, float* __restrict__ out) {
  // per-wave private LDS tile: 16 rows x 68 f32 (pad 64->68 breaks bank align)
  __shared__ float hbuf[4][16 * 68];

  const int tid  = threadIdx.x;
  const int lane = tid & 63;
  const int wid  = tid >> 6;
  const int c    = lane & 15;  // fragment row/col index
  const int g    = lane >> 4;  // k-group
  float* hw      = hbuf[wid];

  const f4* W0v = (const f4*)W0;
  const f4* W1v = (const f4*)W1;
  const f4* W2v = (const f4*)W2;
  const f4* xv  = (const f4*)x;

  // ---- load weights once, keep as bf16 B-fragments in registers ----
  bf16x8 w0f[4], w1f[4][2], w2f[2];
  float b0c[4], b1c[4];
#pragma unroll
  for (int t = 0; t < 4; ++t) {
    const int j = 16 * t + c;  // output-feature (B col) index
    // W0 row j: k 4g..4g+3 and 16+4g..16+4g+3   (row stride 32 f32 = 8 f4)
    f4 wa = W0v[j * 8 + g];
    f4 wb = W0v[j * 8 + 4 + g];
    w0f[t] = cvt8(wa, wb);
    b0c[t] = b0[j];
    b1c[t] = b1[j];
#pragma unroll
    for (int kk = 0; kk < 2; ++kk) {  // W1 row stride 64 f32 = 16 f4
      f4 va = W1v[j * 16 + 8 * kk + g];
      f4 vb = W1v[j * 16 + 8 * kk + 4 + g];
      w1f[t][kk] = cvt8(va, vb);
    }
  }
  {
    const int j   = c & 3;                   // W2 has 4 rows
    const float m = (c < 4) ? 1.0f : 0.0f;   // zero cols 4..15
#pragma unroll
    for (int kk = 0; kk < 2; ++kk) {
      f4 va = W2v[j * 16 + 8 * kk + g] * m;
      f4 vb = W2v[j * 16 + 8 * kk + 4 + g] * m;
      w2f[kk] = cvt8(va, vb);
    }
  }
  const float bb2 = (c < 4) ? b2[c] : 0.0f;

  const int rowbase0 = blockIdx.x * ROWS_PER_BLOCK + wid * (TILES_PER_WAVE * 16);

  for (int i = 0; i < TILES_PER_WAVE; ++i) {
    const int rb  = rowbase0 + i * 16;
    const int row = rb + c;

    // ---- layer 0: A = x tile (16x32), hi/lo split ----
    f4 p0 = xv[row * 8 + g];      // cols 4g..4g+3
    f4 p1 = xv[row * 8 + 4 + g];  // cols 16+4g..
    bf16x8 axh, axl;
    split8(p0, p1, axh, axl);

    f4 acc0[4] = {{0.f, 0.f, 0.f, 0.f},
                  {0.f, 0.f, 0.f, 0.f},
                  {0.f, 0.f, 0.f, 0.f},
                  {0.f, 0.f, 0.f, 0.f}};
#pragma unroll
    for (int t = 0; t < 4; ++t) {
      acc0[t] = MFMA(axh, w0f[t], acc0[t]);
      acc0[t] = MFMA(axl, w0f[t], acc0[t]);
    }

    // bias + relu -> LDS (D layout: col=lane&15, row=4*(lane>>4)+reg)
#pragma unroll
    for (int t = 0; t < 4; ++t)
#pragma unroll
      for (int r = 0; r < 4; ++r) {
        float v = fmaxf(acc0[t][r] + b0c[t], 0.0f);
        hw[(4 * g + r) * 68 + 16 * t + c] = v;
      }

    // ---- layer 1: A = h0 (16x64), K = 64 -> 2 k-blocks ----
    bf16x8 ah[2], al[2];
#pragma unroll
    for (int kk = 0; kk < 2; ++kk) {
      f4 q0 = *(const f4*)&hw[c * 68 + 32 * kk + 4 * g];
      f4 q1 = *(const f4*)&hw[c * 68 + 32 * kk + 16 + 4 * g];
      split8(q0, q1, ah[kk], al[kk]);
    }
    f4 acc1[4] = {{0.f, 0.f, 0.f, 0.f},
                  {0.f, 0.f, 0.f, 0.f},
                  {0.f, 0.f, 0.f, 0.f},
                  {0.f, 0.f, 0.f, 0.f}};
#pragma unroll
    for (int t = 0; t < 4; ++t)
#pragma unroll
      for (int kk = 0; kk < 2; ++kk) {
        acc1[t] = MFMA(ah[kk], w1f[t][kk], acc1[t]);
        acc1[t] = MFMA(al[kk], w1f[t][kk], acc1[t]);
      }

    // bias + relu -> LDS (reuse buffer; per-wave DS ops are in-order)
#pragma unroll
    for (int t = 0; t < 4; ++t)
#pragma unroll
      for (int r = 0; r < 4; ++r) {
        float v = fmaxf(acc1[t][r] + b1c[t], 0.0f);
        hw[(4 * g + r) * 68 + 16 * t + c] = v;
      }

    // ---- layer 2: A = h1 (16x64), B = W2^T (cols 0-3 valid) ----
    bf16x8 ch[2], cl[2];
#pragma unroll
    for (int kk = 0; kk < 2; ++kk) {
      f4 q0 = *(const f4*)&hw[c * 68 + 32 * kk + 4 * g];
      f4 q1 = *(const f4*)&hw[c * 68 + 32 * kk + 16 + 4 * g];
      split8(q0, q1, ch[kk], cl[kk]);
    }
    f4 acc2 = {bb2, bb2, bb2, bb2};  // bias via C-input
#pragma unroll
    for (int kk = 0; kk < 2; ++kk) {
      acc2 = MFMA(ch[kk], w2f[kk], acc2);
      acc2 = MFMA(cl[kk], w2f[kk], acc2);
    }

    // ---- epilogue: compact 16x4 tile so the wave stores 256B coalesced ----
    // dest lane l -> (row=l>>2, o=l&3); src lane = (l&3)+16*(l>>4), reg=(l>>2)&3
    const int srcl = (lane & 3) + ((lane >> 4) << 4);
    const int rsel = (lane >> 2) & 3;
    float vsel = 0.0f;
#pragma unroll
    for (int r = 0; r < 4; ++r) {
      float tr = __shfl(acc2[r], srcl, 64);
      vsel = (rsel == r) ? tr : vsel;
    }
    out[rb * 4 + lane] = vsel;
  }
}

extern "C" void kernel_launch(void* const* d_in, const int* in_sizes, int n_in,
                              void* d_out, int out_size, void* d_ws,
                              size_t ws_size, hipStream_t stream) {
  const float* x  = (const float*)d_in[0];
  const float* W0 = (const float*)d_in[1];
  const float* b0 = (const float*)d_in[2];
  const float* W1 = (const float*)d_in[3];
  const float* b1 = (const float*)d_in[4];
  const float* W2 = (const float*)d_in[5];
  const float* b2 = (const float*)d_in[6];
  float* out      = (float*)d_out;

  const int N    = in_sizes[0] / 32;      // 2097152
  const int grid = N / ROWS_PER_BLOCK;    // 2048 (N divisible by 1024)

  fastmlp_kernel<<<grid, 256, 0, stream>>>(x, W0, b0, W1, b1, W2, b2, out);
}

// Round 4
// 388.951 us; speedup vs baseline: 1.0127x; 1.0127x over previous
//
#include <hip/hip_runtime.h>

// Fused MLP: relu(x@W0^T+b0) -> relu(@W1^T+b1) -> @W2^T+b2
// x: [N,32] f32, W0: [64,32], W1: [64,64], W2: [4,64], out: [N,4] f32.
// Memory-bound: 288 MB traffic -> ~46us roofline @6.3TB/s.
//
// R2 strategy: ALL layers computed operand-swapped (D = W_tile x h^T).
// With the mfma_f32_16x16x32_bf16 fragment mapping (A row = lane&15,
// B col = lane&15, D col = lane&15 / row = 4*(lane>>4)+reg), the swapped
// D-layout of layer L (lane holds features {16t+4g+r} of ONE sample) is
// exactly the B-fragment layer L+1 needs (features {32kk+4g+e} and
// {32kk+16+4g+e} -> tiles 2kk,2kk+1, elem e=r). Layer handoff is pure
// lane-local register re-indexing: NO LDS, NO shfl, NO barriers.
// Hi/lo split-bf16 on activations keeps ~fp32 precision (only weight
// quantization error remains; measured absmax 0.0156 in R1).

typedef float f4 __attribute__((ext_vector_type(4)));
typedef __bf16 bf16x8 __attribute__((ext_vector_type(8)));

#define MFMA(a, b, c) __builtin_amdgcn_mfma_f32_16x16x32_bf16(a, b, c, 0, 0, 0)

__device__ __forceinline__ bf16x8 cvt8(f4 a, f4 b) {
  bf16x8 o;
#pragma unroll
  for (int e = 0; e < 4; ++e) {
    o[e]     = (__bf16)a[e];
    o[e + 4] = (__bf16)b[e];
  }
  return o;
}

__device__ __forceinline__ void split8(f4 a, f4 b, bf16x8& hi, bf16x8& lo) {
#pragma unroll
  for (int e = 0; e < 4; ++e) {
    float fa = a[e], fb = b[e];
    __bf16 ha = (__bf16)fa, hb = (__bf16)fb;
    hi[e]     = ha;
    hi[e + 4] = hb;
    lo[e]     = (__bf16)(fa - (float)ha);
    lo[e + 4] = (__bf16)(fb - (float)hb);
  }
}

#define TILES_PER_WAVE 16
#define ROWS_PER_BLOCK (4 * TILES_PER_WAVE * 16)  // 1024

__global__ __launch_bounds__(256) void fastmlp_kernel(
    const float* __restrict__ x, const float* __restrict__ W0,
    const float* __restrict__ b0, const float* __restrict__ W1,
    const float* __restrict__ b1, const float* __restrict__ W2,
    const float* __restrict__ b2, float* __restrict__ out) {
  const int tid  = threadIdx.x;
  const int lane = tid & 63;
  const int wid  = tid >> 6;
  const int c    = lane & 15;  // A-row / B-col / D-col index
  const int g    = lane >> 4;  // k-group

  const f4* W0v = (const f4*)W0;
  const f4* W1v = (const f4*)W1;
  const f4* W2v = (const f4*)W2;
  const f4* xv  = (const f4*)x;
  f4* outv      = (f4*)out;

  // ---- weights as A-fragments (lane holds row 16t+c, k = 4g+e / 16+4g+e) --
  bf16x8 w0f[4], w1f[4][2], w2f[2];
  f4 b0f[4], b1f[4];  // bias fragments matching D rows (feature 16t+4g+r)
#pragma unroll
  for (int t = 0; t < 4; ++t) {
    const int m = 16 * t + c;  // out-feature row
    w0f[t] = cvt8(W0v[m * 8 + g], W0v[m * 8 + 4 + g]);  // row stride 32f = 8 f4
#pragma unroll
    for (int kk = 0; kk < 2; ++kk)  // row stride 64f = 16 f4
      w1f[t][kk] = cvt8(W1v[m * 16 + 8 * kk + g], W1v[m * 16 + 8 * kk + 4 + g]);
    b0f[t] = ((const f4*)b0)[4 * t + g];
    b1f[t] = ((const f4*)b1)[4 * t + g];
  }
  {
    const int j   = c & 3;                  // W2 has 4 valid rows
    const float m = (c < 4) ? 1.0f : 0.0f;  // zero A rows 4..15
#pragma unroll
    for (int kk = 0; kk < 2; ++kk)
      w2f[kk] = cvt8(W2v[j * 16 + 8 * kk + g] * m,
                     W2v[j * 16 + 8 * kk + 4 + g] * m);
  }
  const f4 b2v  = *(const f4*)b2;  // lane-uniform 16B load (valid)
  const f4 zero = {0.f, 0.f, 0.f, 0.f};
  const f4 acc2init = (g == 0) ? b2v : zero;

  const int rowbase0 = blockIdx.x * ROWS_PER_BLOCK + wid * (TILES_PER_WAVE * 16);

  // software-prefetch the first x tile
  f4 p0 = xv[(rowbase0 + c) * 8 + g];
  f4 p1 = xv[(rowbase0 + c) * 8 + 4 + g];

#pragma unroll 1
  for (int i = 0; i < TILES_PER_WAVE; ++i) {
    const int rb = rowbase0 + i * 16;
    const f4 cur0 = p0, cur1 = p1;
    if (i + 1 < TILES_PER_WAVE) {  // issue next tile's loads early
      p0 = xv[(rb + 16 + c) * 8 + g];
      p1 = xv[(rb + 16 + c) * 8 + 4 + g];
    }

    // ---- layer 0: D0 = W0 x x^T  (B = x^T: col=sample c, k=features) ----
    bf16x8 axh, axl;
    split8(cur0, cur1, axh, axl);
    f4 acc0[4];
#pragma unroll
    for (int t = 0; t < 4; ++t) {
      acc0[t] = b0f[t];  // bias via C-input
      acc0[t] = MFMA(w0f[t], axh, acc0[t]);
      acc0[t] = MFMA(w0f[t], axl, acc0[t]);
    }
    f4 h0[4];
#pragma unroll
    for (int t = 0; t < 4; ++t)
#pragma unroll
      for (int r = 0; r < 4; ++r) h0[t][r] = fmaxf(acc0[t][r], 0.0f);

    // ---- layer 1: lane-local handoff, B-frag kk from h0[2kk],h0[2kk+1] ----
    bf16x8 bh[2], bl[2];
#pragma unroll
    for (int kk = 0; kk < 2; ++kk) split8(h0[2 * kk], h0[2 * kk + 1], bh[kk], bl[kk]);
    f4 acc1[4];
#pragma unroll
    for (int t = 0; t < 4; ++t) {
      acc1[t] = b1f[t];
#pragma unroll
      for (int kk = 0; kk < 2; ++kk) {
        acc1[t] = MFMA(w1f[t][kk], bh[kk], acc1[t]);
        acc1[t] = MFMA(w1f[t][kk], bl[kk], acc1[t]);
      }
    }
    f4 h1[4];
#pragma unroll
    for (int t = 0; t < 4; ++t)
#pragma unroll
      for (int r = 0; r < 4; ++r) h1[t][r] = fmaxf(acc1[t][r], 0.0f);

    // ---- layer 2: D2 rows = out-dims (only g==0 lanes hold valid rows) ----
    bf16x8 ch[2], cl[2];
#pragma unroll
    for (int kk = 0; kk < 2; ++kk) split8(h1[2 * kk], h1[2 * kk + 1], ch[kk], cl[kk]);
    f4 acc2 = acc2init;
#pragma unroll
    for (int kk = 0; kk < 2; ++kk) {
      acc2 = MFMA(w2f[kk], ch[kk], acc2);
      acc2 = MFMA(w2f[kk], cl[kk], acc2);
    }

    // ---- epilogue: lane (c, g==0) holds out[rb+c][0..3] ----
    if (g == 0) outv[rb + c] = acc2;
  }
}

extern "C" void kernel_launch(void* const* d_in, const int* in_sizes, int n_in,
                              void* d_out, int out_size, void* d_ws,
                              size_t ws_size, hipStream_t stream) {
  const float* x  = (const float*)d_in[0];
  const float* W0 = (const float*)d_in[1];
  const float* b0 = (const float*)d_in[2];
  const float* W1 = (const float*)d_in[3];
  const float* b1 = (const float*)d_in[4];
  const float* W2 = (const float*)d_in[5];
  const float* b2 = (const float*)d_in[6];
  float* out      = (float*)d_out;

  const int N    = in_sizes[0] / 32;    // 2097152
  const int grid = N / ROWS_PER_BLOCK;  // 2048

  fastmlp_kernel<<<grid, 256, 0, stream>>>(x, W0, b0, W1, b1, W2, b2, out);
}